// Round 13
// baseline (391.015 us; speedup 1.0000x reference)
//
#include <hip/hip_runtime.h>
#include <hip/hip_bf16.h>

#define B_N 8192
#define D_K 256
#define BM  256
#define BN  32
#define JSPLIT 16
#define JSPAN (B_N / JSPLIT)     // 512
#define NTILE (JSPAN / BN)       // 16
#define NCLS 1024
#define GRID 512
#define INVT 14.285714285714286f
#define C1   20.60992907f        // INVT * log2(e)
#define MAGIC 0x1357ACEDu

typedef __bf16 bf16x8 __attribute__((ext_vector_type(8)));
typedef float  f32x16 __attribute__((ext_vector_type(16)));
typedef float  f32x4  __attribute__((ext_vector_type(4)));

#define AS1 __attribute__((address_space(1)))
#define AS3 __attribute__((address_space(3)))

__device__ __forceinline__ unsigned short f32_to_bf16_rne(float f) {
    unsigned int u = __float_as_uint(f);
    unsigned int r = (u + 0x7FFFu + ((u >> 16) & 1u)) >> 16;
    return (unsigned short)r;
}
__device__ __forceinline__ float bf16_to_f32(unsigned short u) {
    return __uint_as_float(((unsigned int)u) << 16);
}

// Manual grid barrier for a fully-co-resident grid (512 blocks = 2/CU by
// construction). bar[0..1] = phase counters, bar[2] = init-ready flag
// (d_ws is poisoned 0xAA each launch; block 0 re-inits, others gate on
// MAGIC). Device-scope atomics + threadfence handle cross-XCD visibility.
// Spin is capped: a broken assumption fails loud, never hangs.
__device__ __forceinline__ void grid_barrier(unsigned int* bar, int idx) {
    __threadfence();                 // release: my writes visible device-wide
    __syncthreads();                 // all block threads have flushed
    if (threadIdx.x == 0) {
        unsigned int spins = 0;
        while (__hip_atomic_load(&bar[2], __ATOMIC_ACQUIRE,
                                 __HIP_MEMORY_SCOPE_AGENT) != MAGIC) {
            if (++spins > 50000000u) break;
            __builtin_amdgcn_s_sleep(1);
        }
        __hip_atomic_fetch_add(&bar[idx], 1u, __ATOMIC_ACQ_REL,
                               __HIP_MEMORY_SCOPE_AGENT);
        spins = 0;
        while (__hip_atomic_load(&bar[idx], __ATOMIC_ACQUIRE,
                                 __HIP_MEMORY_SCOPE_AGENT) < GRID) {
            if (++spins > 50000000u) break;
            __builtin_amdgcn_s_sleep(1);
        }
    }
    __syncthreads();
    __threadfence();                 // acquire: drop stale cached lines
}

// One persistent kernel: norm -> barrier -> denom-GEMM + per-class centroid
// -> barrier -> per-row loss. Replaces 3-4 dispatches (~50us overhead).
__launch_bounds__(256, 2)
__global__ void fused_kernel(const float* __restrict__ emb,
                             const int* __restrict__ labels,
                             unsigned short* __restrict__ en,
                             float* __restrict__ s_part,
                             float* __restrict__ Cmat,
                             int* __restrict__ hist,
                             float* __restrict__ self_arr,
                             unsigned int* __restrict__ bar,
                             float* __restrict__ out) {
    __shared__ __align__(16) unsigned short Bls[2][BN * D_K];  // 2 x 16 KB
    __shared__ float part[4];
    __shared__ int   cntb[4];

    const int t = threadIdx.x;
    const int l = t & 63;
    const int w = t >> 6;
    const int b = blockIdx.x;

    // barrier init (gated by MAGIC ready-flag; ws is 0xAA-poisoned)
    if (b == 0 && t == 0) {
        __hip_atomic_store(&bar[0], 0u, __ATOMIC_RELAXED,
                           __HIP_MEMORY_SCOPE_AGENT);
        __hip_atomic_store(&bar[1], 0u, __ATOMIC_RELAXED,
                           __HIP_MEMORY_SCOPE_AGENT);
        __hip_atomic_store(&bar[2], MAGIC, __ATOMIC_RELEASE,
                           __HIP_MEMORY_SCOPE_AGENT);
        out[0] = 0.0f;
    }

    // ---------------- phase 1: normalize 16 rows/block, exact self ---------
    #pragma unroll
    for (int r = 0; r < 4; ++r) {
        const int row = b * 16 + w * 4 + r;
        f32x4 x =
            *reinterpret_cast<const f32x4*>(emb + (size_t)row * D_K + l * 4);
        float ss = x[0]*x[0] + x[1]*x[1] + x[2]*x[2] + x[3]*x[3];
        #pragma unroll
        for (int m = 1; m < 64; m <<= 1) ss += __shfl_xor(ss, m, 64);
        float sc = 1.0f / fmaxf(sqrtf(ss), 1e-12f);
        ushort4 o;
        o.x = f32_to_bf16_rne(x[0] * sc); o.y = f32_to_bf16_rne(x[1] * sc);
        o.z = f32_to_bf16_rne(x[2] * sc); o.w = f32_to_bf16_rne(x[3] * sc);
        *reinterpret_cast<ushort4*>(en + (size_t)row * D_K + l * 4) = o;
        float y0 = bf16_to_f32(o.x), y1 = bf16_to_f32(o.y),
              y2 = bf16_to_f32(o.z), y3 = bf16_to_f32(o.w);
        float s2 = y0*y0 + y1*y1 + y2*y2 + y3*y3;
        #pragma unroll
        for (int m = 1; m < 64; m <<= 1) s2 += __shfl_xor(s2, m, 64);
        if (l == 0) self_arr[row] = s2;
    }

    grid_barrier(bar, 0);

    // ---------------- phase 2a: softmax-denominator GEMM (R7 config) -------
    {
        const int ir = l & 31;
        const int h  = l >> 5;
        const int xcd    = b & 7;
        const int local  = b >> 3;             // [0,64)
        const int itile  = xcd * 4 + (local & 3);
        const int jsplit = local >> 2;         // [0,16)
        const int ibase  = itile * BM;
        const int j0     = jsplit * JSPAN;

        bf16x8 bi0[16], bi1[16];
        {
            const unsigned short* ap0 =
                en + (size_t)(ibase + w * 64 + ir) * D_K + h * 8;
            const unsigned short* ap1 = ap0 + 32 * D_K;
            #pragma unroll
            for (int ks = 0; ks < 16; ++ks) {
                bi0[ks] = *reinterpret_cast<const bf16x8*>(ap0 + ks * 16);
                bi1[ks] = *reinterpret_cast<const bf16x8*>(ap1 + ks * 16);
            }
        }

        const int srcm = (t & 31) ^ ((t >> 5) & 7);
        const unsigned short* gb =
            en + (size_t)(j0 + (t >> 5)) * D_K + srcm * 8;
        const char* abase0 = (const char*)Bls[0] + (size_t)ir * 512;
        const char* abase1 = (const char*)Bls[1] + (size_t)ir * 512;
        const int xr = (ir & 7) << 4;

        float sA0 = 0.f, sA1 = 0.f, sB0 = 0.f, sB1 = 0.f;

#define STAGE(bufp, itv)                                                     \
    {                                                                        \
        const unsigned short* gsrc = gb + (size_t)(itv) * (BN * D_K);        \
        char* ldst = (char*)(bufp) + t * 16;                                 \
        _Pragma("unroll")                                                    \
        for (int rd = 0; rd < 4; ++rd)                                       \
            __builtin_amdgcn_global_load_lds(                                \
                (const AS1 void*)(gsrc + rd * 2048),                         \
                (AS3 void*)(ldst + rd * 4096), 16, 0, 0);                    \
    }

#define TILE_COMPUTE(arow_b)                                                 \
    {                                                                        \
        f32x16 a0, a1;                                                       \
        _Pragma("unroll")                                                    \
        for (int q = 0; q < 16; ++q) { a0[q] = 0.0f; a1[q] = 0.0f; }         \
        __builtin_amdgcn_s_setprio(1);                                       \
        _Pragma("unroll")                                                    \
        for (int ks = 0; ks < 16; ++ks) {                                    \
            const bf16x8 af = *reinterpret_cast<const bf16x8*>(              \
                (arow_b) + ((((ks << 1) | h) << 4) ^ xr));                   \
            a0 = __builtin_amdgcn_mfma_f32_32x32x16_bf16(af, bi0[ks], a0,    \
                                                         0, 0, 0);           \
            a1 = __builtin_amdgcn_mfma_f32_32x32x16_bf16(af, bi1[ks], a1,    \
                                                         0, 0, 0);           \
        }                                                                    \
        __builtin_amdgcn_s_setprio(0);                                       \
        _Pragma("unroll")                                                    \
        for (int q = 0; q < 16; ++q) {                                       \
            float e0 = __builtin_amdgcn_exp2f(fmaf(a0[q], C1, -C1));         \
            float e1 = __builtin_amdgcn_exp2f(fmaf(a1[q], C1, -C1));         \
            if (q & 1) { sA1 += e0; sB1 += e1; }                             \
            else       { sA0 += e0; sB0 += e1; }                             \
        }                                                                    \
    }

        STAGE(Bls[0], 0);
        __syncthreads();
        for (int it = 0; it < NTILE; it += 2) {
            if (it + 1 < NTILE) STAGE(Bls[1], it + 1);
            TILE_COMPUTE(abase0);
            __syncthreads();
            if (it + 2 < NTILE) STAGE(Bls[0], it + 2);
            TILE_COMPUTE(abase1);
            __syncthreads();
        }
#undef STAGE
#undef TILE_COMPUTE

        float sA = sA0 + sA1, sB = sB0 + sB1;
        sA += __shfl_xor(sA, 32, 64);
        sB += __shfl_xor(sB, 32, 64);
        if (h == 0) {
            const size_t base = (size_t)jsplit * B_N + ibase + w * 64 + ir;
            s_part[base]      = sA;
            s_part[base + 32] = sB;
        }
    }

    // ---------------- phase 2b: per-class centroid + count (deterministic) -
    {
        float* red = (float*)&Bls[0][0];   // 4 KB overlay; Bls reads done
        #pragma unroll
        for (int cc = 0; cc < 2; ++cc) {
            const int c = 2 * b + cc;
            float a0 = 0.f, a1 = 0.f, a2 = 0.f, a3 = 0.f;
            int cnt = 0;
            for (int ch = w; ch < B_N / 64; ch += 4) {
                int lj = labels[ch * 64 + l];
                unsigned long long m = __ballot(lj == c);
                cnt += (int)__popcll(m);
                while (m) {
                    int js = __ffsll((long long)m) - 1;
                    m &= m - 1;
                    const int j = ch * 64 + js;
                    ushort4 eu = *reinterpret_cast<const ushort4*>(
                        en + (size_t)j * D_K + l * 4);
                    a0 += bf16_to_f32(eu.x); a1 += bf16_to_f32(eu.y);
                    a2 += bf16_to_f32(eu.z); a3 += bf16_to_f32(eu.w);
                }
            }
            __syncthreads();
            red[w * 256 + l * 4 + 0] = a0;
            red[w * 256 + l * 4 + 1] = a1;
            red[w * 256 + l * 4 + 2] = a2;
            red[w * 256 + l * 4 + 3] = a3;
            if (l == 0) cntb[w] = cnt;
            __syncthreads();
            {
                float v = red[t] + red[256 + t] + red[512 + t] + red[768 + t];
                Cmat[(size_t)c * D_K + t] = v;
                if (t == 0) hist[c] = cntb[0] + cntb[1] + cntb[2] + cntb[3];
            }
            __syncthreads();
        }
    }

    grid_barrier(bar, 1);

    // ---------------- phase 3: per-row loss, one atomic per block ----------
    {
        float lsum = 0.0f;
        #pragma unroll
        for (int r = 0; r < 4; ++r) {
            const int i = b * 16 + w * 4 + r;
            float sv = (l < JSPLIT) ? s_part[(size_t)l * B_N + i] : 0.0f;
            #pragma unroll
            for (int mm = 1; mm < 16; mm <<= 1) sv += __shfl_xor(sv, mm, 64);
            const int lab = labels[i];
            ushort4 eu = *reinterpret_cast<const ushort4*>(
                en + (size_t)i * D_K + l * 4);
            f32x4 c4 = *reinterpret_cast<const f32x4*>(
                Cmat + (size_t)lab * D_K + l * 4);
            float d = bf16_to_f32(eu.x) * c4[0] + bf16_to_f32(eu.y) * c4[1]
                    + bf16_to_f32(eu.z) * c4[2] + bf16_to_f32(eu.w) * c4[3];
            #pragma unroll
            for (int mm = 1; mm < 64; mm <<= 1) d += __shfl_xor(d, mm, 64);
            if (l == 0) {
                float ps = d - self_arr[i];
                int pc = hist[lab] - 1;
                lsum += (pc > 0)
                    ? (INVT + logf(sv)) - ps * INVT / (float)pc : 0.0f;
            }
        }
        if (l == 0) part[w] = lsum;
        __syncthreads();
        if (t == 0)
            atomicAdd(out,
                      (part[0] + part[1] + part[2] + part[3]) * (1.0f / B_N));
    }
}

extern "C" void kernel_launch(void* const* d_in, const int* in_sizes, int n_in,
                              void* d_out, int out_size, void* d_ws, size_t ws_size,
                              hipStream_t stream) {
    const float* emb    = (const float*)d_in[0];
    const int*   labels = (const int*)d_in[1];
    float*       out    = (float*)d_out;

    unsigned short* en = (unsigned short*)d_ws;                       // 4 MB
    float* s_part   = (float*)((char*)d_ws + (size_t)B_N * D_K * 2);  // 512 KB
    float* Cmat     = s_part + (size_t)JSPLIT * B_N;                  // 1 MB
    int*   hist     = (int*)(Cmat + (size_t)NCLS * D_K);              // 4 KB
    float* self_arr = (float*)(hist + NCLS);                          // 32 KB
    unsigned int* bar = (unsigned int*)(self_arr + B_N);              // 64 B

    hipLaunchKernelGGL(fused_kernel, dim3(GRID), dim3(256), 0, stream,
                       emb, labels, en, s_part, Cmat, hist, self_arr, bar,
                       out);
}

// Round 14
// 277.427 us; speedup vs baseline: 1.4094x; 1.4094x over previous
//
#include <hip/hip_runtime.h>
#include <hip/hip_bf16.h>

#define B_N 8192
#define D_K 256
#define BM  256
#define BN  32
#define JSPLIT 16
#define JSPAN (B_N / JSPLIT)     // 512
#define NTILE (JSPAN / BN)       // 16
#define NCLS 1024
#define GRID 512
#define INVT 14.285714285714286f
#define C1   20.60992907f        // INVT * log2(e)
#define MAGIC  0x1357ACEDu
#define RELMAG 0xBEEF0001u

typedef __bf16 bf16x8 __attribute__((ext_vector_type(8)));
typedef float  f32x16 __attribute__((ext_vector_type(16)));
typedef float  f32x4  __attribute__((ext_vector_type(4)));

#define AS1 __attribute__((address_space(1)))
#define AS3 __attribute__((address_space(3)))

__device__ __forceinline__ unsigned short f32_to_bf16_rne(float f) {
    unsigned int u = __float_as_uint(f);
    unsigned int r = (u + 0x7FFFu + ((u >> 16) & 1u)) >> 16;
    return (unsigned short)r;
}
__device__ __forceinline__ float bf16_to_f32(unsigned short u) {
    return __uint_as_float(((unsigned int)u) << 16);
}

// Decontended grid barrier for a co-resident grid (512 blocks = 2/CU).
// Layout (uint indices, 256B-separated lines): [0]=cnt0, [64]=cnt1,
// [128..129]=release flags, [192]=init gate. Counter lines have NO pollers
// (RMW storm pipelines in ~2us); release polled RELAXED at ~1.8us interval
// (aggregate ~0.3G/s, below one L2 bank's service rate -- R13's collapse was
// 1.3G/s ACQUIRE polls on the SAME line as the counter). Last arriver
// releases. Spin caps fail loud, never hang.
__device__ __forceinline__ void grid_barrier(unsigned int* bar, int idx) {
    __threadfence();                 // release my writes
    __syncthreads();
    if (threadIdx.x == 0) {
        unsigned int spins = 0;
        while (__hip_atomic_load(&bar[192], __ATOMIC_ACQUIRE,
                                 __HIP_MEMORY_SCOPE_AGENT) != MAGIC) {
            if (++spins > (1u << 20)) break;
            __builtin_amdgcn_s_sleep(16);
        }
        unsigned int arrived = __hip_atomic_fetch_add(
            &bar[idx * 64], 1u, __ATOMIC_ACQ_REL, __HIP_MEMORY_SCOPE_AGENT);
        if (arrived == GRID - 1) {
            __hip_atomic_store(&bar[128 + idx], RELMAG, __ATOMIC_RELEASE,
                               __HIP_MEMORY_SCOPE_AGENT);
        } else {
            spins = 0;
            while (__hip_atomic_load(&bar[128 + idx], __ATOMIC_RELAXED,
                                     __HIP_MEMORY_SCOPE_AGENT) != RELMAG) {
                if (++spins > (1u << 20)) break;
                __builtin_amdgcn_s_sleep(64);
            }
        }
    }
    __syncthreads();
    __threadfence();                 // acquire: drop stale cached lines
}

// One persistent kernel: norm -> barrier -> denom-GEMM + per-class centroid
// -> barrier -> per-row loss. 1 dispatch (~30us fixed + ~7us/dispatch saved).
__launch_bounds__(256, 2)
__global__ void fused_kernel(const float* __restrict__ emb,
                             const int* __restrict__ labels,
                             unsigned short* __restrict__ en,
                             float* __restrict__ s_part,
                             float* __restrict__ Cmat,
                             int* __restrict__ hist,
                             float* __restrict__ self_arr,
                             unsigned int* __restrict__ bar,
                             float* __restrict__ out) {
    __shared__ __align__(16) unsigned short Bls[2][BN * D_K];  // 2 x 16 KB
    __shared__ float part[4];
    __shared__ int   cntb[4];

    const int t = threadIdx.x;
    const int l = t & 63;
    const int w = t >> 6;
    const int b = blockIdx.x;

    // barrier init (gated by MAGIC; d_ws is 0xAA-poisoned each launch)
    if (b == 0 && t == 0) {
        __hip_atomic_store(&bar[0],   0u, __ATOMIC_RELAXED,
                           __HIP_MEMORY_SCOPE_AGENT);
        __hip_atomic_store(&bar[64],  0u, __ATOMIC_RELAXED,
                           __HIP_MEMORY_SCOPE_AGENT);
        __hip_atomic_store(&bar[128], 0u, __ATOMIC_RELAXED,
                           __HIP_MEMORY_SCOPE_AGENT);
        __hip_atomic_store(&bar[129], 0u, __ATOMIC_RELAXED,
                           __HIP_MEMORY_SCOPE_AGENT);
        __hip_atomic_store(&bar[192], MAGIC, __ATOMIC_RELEASE,
                           __HIP_MEMORY_SCOPE_AGENT);
        out[0] = 0.0f;
    }

    // ---------------- phase 1: normalize 16 rows/block, exact self ---------
    #pragma unroll
    for (int r = 0; r < 4; ++r) {
        const int row = b * 16 + w * 4 + r;
        f32x4 x =
            *reinterpret_cast<const f32x4*>(emb + (size_t)row * D_K + l * 4);
        float ss = x[0]*x[0] + x[1]*x[1] + x[2]*x[2] + x[3]*x[3];
        #pragma unroll
        for (int m = 1; m < 64; m <<= 1) ss += __shfl_xor(ss, m, 64);
        float sc = 1.0f / fmaxf(sqrtf(ss), 1e-12f);
        ushort4 o;
        o.x = f32_to_bf16_rne(x[0] * sc); o.y = f32_to_bf16_rne(x[1] * sc);
        o.z = f32_to_bf16_rne(x[2] * sc); o.w = f32_to_bf16_rne(x[3] * sc);
        *reinterpret_cast<ushort4*>(en + (size_t)row * D_K + l * 4) = o;
        float y0 = bf16_to_f32(o.x), y1 = bf16_to_f32(o.y),
              y2 = bf16_to_f32(o.z), y3 = bf16_to_f32(o.w);
        float s2 = y0*y0 + y1*y1 + y2*y2 + y3*y3;
        #pragma unroll
        for (int m = 1; m < 64; m <<= 1) s2 += __shfl_xor(s2, m, 64);
        if (l == 0) self_arr[row] = s2;
    }

    grid_barrier(bar, 0);

    // ---------------- phase 2a: softmax-denominator GEMM (R7 config) -------
    {
        const int ir = l & 31;
        const int h  = l >> 5;
        const int xcd    = b & 7;
        const int local  = b >> 3;             // [0,64)
        const int itile  = xcd * 4 + (local & 3);
        const int jsplit = local >> 2;         // [0,16)
        const int ibase  = itile * BM;
        const int j0     = jsplit * JSPAN;

        bf16x8 bi0[16], bi1[16];
        {
            const unsigned short* ap0 =
                en + (size_t)(ibase + w * 64 + ir) * D_K + h * 8;
            const unsigned short* ap1 = ap0 + 32 * D_K;
            #pragma unroll
            for (int ks = 0; ks < 16; ++ks) {
                bi0[ks] = *reinterpret_cast<const bf16x8*>(ap0 + ks * 16);
                bi1[ks] = *reinterpret_cast<const bf16x8*>(ap1 + ks * 16);
            }
        }

        const int srcm = (t & 31) ^ ((t >> 5) & 7);
        const unsigned short* gb =
            en + (size_t)(j0 + (t >> 5)) * D_K + srcm * 8;
        const char* abase0 = (const char*)Bls[0] + (size_t)ir * 512;
        const char* abase1 = (const char*)Bls[1] + (size_t)ir * 512;
        const int xr = (ir & 7) << 4;

        float sA0 = 0.f, sA1 = 0.f, sB0 = 0.f, sB1 = 0.f;

#define STAGE(bufp, itv)                                                     \
    {                                                                        \
        const unsigned short* gsrc = gb + (size_t)(itv) * (BN * D_K);        \
        char* ldst = (char*)(bufp) + t * 16;                                 \
        _Pragma("unroll")                                                    \
        for (int rd = 0; rd < 4; ++rd)                                       \
            __builtin_amdgcn_global_load_lds(                                \
                (const AS1 void*)(gsrc + rd * 2048),                         \
                (AS3 void*)(ldst + rd * 4096), 16, 0, 0);                    \
    }

#define TILE_COMPUTE(arow_b)                                                 \
    {                                                                        \
        f32x16 a0, a1;                                                       \
        _Pragma("unroll")                                                    \
        for (int q = 0; q < 16; ++q) { a0[q] = 0.0f; a1[q] = 0.0f; }         \
        __builtin_amdgcn_s_setprio(1);                                       \
        _Pragma("unroll")                                                    \
        for (int ks = 0; ks < 16; ++ks) {                                    \
            const bf16x8 af = *reinterpret_cast<const bf16x8*>(              \
                (arow_b) + ((((ks << 1) | h) << 4) ^ xr));                   \
            a0 = __builtin_amdgcn_mfma_f32_32x32x16_bf16(af, bi0[ks], a0,    \
                                                         0, 0, 0);           \
            a1 = __builtin_amdgcn_mfma_f32_32x32x16_bf16(af, bi1[ks], a1,    \
                                                         0, 0, 0);           \
        }                                                                    \
        __builtin_amdgcn_s_setprio(0);                                       \
        _Pragma("unroll")                                                    \
        for (int q = 0; q < 16; ++q) {                                       \
            float e0 = __builtin_amdgcn_exp2f(fmaf(a0[q], C1, -C1));         \
            float e1 = __builtin_amdgcn_exp2f(fmaf(a1[q], C1, -C1));         \
            if (q & 1) { sA1 += e0; sB1 += e1; }                             \
            else       { sA0 += e0; sB0 += e1; }                             \
        }                                                                    \
    }

        STAGE(Bls[0], 0);
        __syncthreads();
        for (int it = 0; it < NTILE; it += 2) {
            if (it + 1 < NTILE) STAGE(Bls[1], it + 1);
            TILE_COMPUTE(abase0);
            __syncthreads();
            if (it + 2 < NTILE) STAGE(Bls[0], it + 2);
            TILE_COMPUTE(abase1);
            __syncthreads();
        }
#undef STAGE
#undef TILE_COMPUTE

        float sA = sA0 + sA1, sB = sB0 + sB1;
        sA += __shfl_xor(sA, 32, 64);
        sB += __shfl_xor(sB, 32, 64);
        if (h == 0) {
            const size_t base = (size_t)jsplit * B_N + ibase + w * 64 + ir;
            s_part[base]      = sA;
            s_part[base + 32] = sB;
        }
    }

    // ---------------- phase 2b: per-class centroid + count (deterministic) -
    {
        float* red = (float*)&Bls[0][0];   // 4 KB overlay; Bls reads done
        #pragma unroll
        for (int cc = 0; cc < 2; ++cc) {
            const int c = 2 * b + cc;
            float a0 = 0.f, a1 = 0.f, a2 = 0.f, a3 = 0.f;
            int cnt = 0;
            for (int ch = w; ch < B_N / 64; ch += 4) {
                int lj = labels[ch * 64 + l];
                unsigned long long m = __ballot(lj == c);
                cnt += (int)__popcll(m);
                while (m) {
                    int js = __ffsll((long long)m) - 1;
                    m &= m - 1;
                    const int j = ch * 64 + js;
                    ushort4 eu = *reinterpret_cast<const ushort4*>(
                        en + (size_t)j * D_K + l * 4);
                    a0 += bf16_to_f32(eu.x); a1 += bf16_to_f32(eu.y);
                    a2 += bf16_to_f32(eu.z); a3 += bf16_to_f32(eu.w);
                }
            }
            __syncthreads();
            red[w * 256 + l * 4 + 0] = a0;
            red[w * 256 + l * 4 + 1] = a1;
            red[w * 256 + l * 4 + 2] = a2;
            red[w * 256 + l * 4 + 3] = a3;
            if (l == 0) cntb[w] = cnt;
            __syncthreads();
            {
                float v = red[t] + red[256 + t] + red[512 + t] + red[768 + t];
                Cmat[(size_t)c * D_K + t] = v;
                if (t == 0) hist[c] = cntb[0] + cntb[1] + cntb[2] + cntb[3];
            }
            __syncthreads();
        }
    }

    grid_barrier(bar, 1);

    // ---------------- phase 3: per-row loss, one atomic per block ----------
    {
        float lsum = 0.0f;
        #pragma unroll
        for (int r = 0; r < 4; ++r) {
            const int i = b * 16 + w * 4 + r;
            float sv = (l < JSPLIT) ? s_part[(size_t)l * B_N + i] : 0.0f;
            #pragma unroll
            for (int mm = 1; mm < 16; mm <<= 1) sv += __shfl_xor(sv, mm, 64);
            const int lab = labels[i];
            ushort4 eu = *reinterpret_cast<const ushort4*>(
                en + (size_t)i * D_K + l * 4);
            f32x4 c4 = *reinterpret_cast<const f32x4*>(
                Cmat + (size_t)lab * D_K + l * 4);
            float d = bf16_to_f32(eu.x) * c4[0] + bf16_to_f32(eu.y) * c4[1]
                    + bf16_to_f32(eu.z) * c4[2] + bf16_to_f32(eu.w) * c4[3];
            #pragma unroll
            for (int mm = 1; mm < 64; mm <<= 1) d += __shfl_xor(d, mm, 64);
            if (l == 0) {
                float ps = d - self_arr[i];
                int pc = hist[lab] - 1;
                lsum += (pc > 0)
                    ? (INVT + logf(sv)) - ps * INVT / (float)pc : 0.0f;
            }
        }
        if (l == 0) part[w] = lsum;
        __syncthreads();
        if (t == 0)
            atomicAdd(out,
                      (part[0] + part[1] + part[2] + part[3]) * (1.0f / B_N));
    }
}

extern "C" void kernel_launch(void* const* d_in, const int* in_sizes, int n_in,
                              void* d_out, int out_size, void* d_ws, size_t ws_size,
                              hipStream_t stream) {
    const float* emb    = (const float*)d_in[0];
    const int*   labels = (const int*)d_in[1];
    float*       out    = (float*)d_out;

    unsigned short* en = (unsigned short*)d_ws;                       // 4 MB
    float* s_part   = (float*)((char*)d_ws + (size_t)B_N * D_K * 2);  // 512 KB
    float* Cmat     = s_part + (size_t)JSPLIT * B_N;                  // 1 MB
    int*   hist     = (int*)(Cmat + (size_t)NCLS * D_K);              // 4 KB
    float* self_arr = (float*)(hist + NCLS);                          // 32 KB
    unsigned int* bar = (unsigned int*)(self_arr + B_N);              // 1 KB

    hipLaunchKernelGGL(fused_kernel, dim3(GRID), dim3(256), 0, stream,
                       emb, labels, en, s_part, Cmat, hist, self_arr, bar,
                       out);
}